// Round 2
// baseline (63.394 us; speedup 1.0000x reference)
//
#include <hip/hip_runtime.h>

#define NUM_BINS 10
#define GRID1 2048
#define BLOCK 256
// elems/thread = 16,777,216 / (2048*256) = 32 -> packed 8-bit fields can't
// overflow (max 32 per field per thread; 128 after 2 butterfly rounds; 2048
// in 16-bit fields after full wave reduce).

template <bool USE_WS>
__global__ __launch_bounds__(BLOCK) void hist_pass1(
    const float* __restrict__ res,
    const float* __restrict__ gt,
    int* __restrict__ dst,   // USE_WS: partials [gridDim.x*32]; else: out[20] (atomic)
    int n4)
{
    const int tid  = threadIdx.x;
    const int lane = tid & 63;
    const int wv   = tid >> 6;

    // 20 counters packed into 5 regs x 4 byte-fields: counter c -> reg c>>2, byte c&3.
    int p[5] = {0, 0, 0, 0, 0};

    const float4* __restrict__ res4 = (const float4*)res;
    const float4* __restrict__ gt4  = (const float4*)gt;

    const int stride = gridDim.x * BLOCK;
    for (int i = blockIdx.x * BLOCK + tid; i < n4; i += stride) {
        float4 r = res4[i];
        float4 g = gt4[i];
        float rv[4] = {r.x, r.y, r.z, r.w};
        float gv[4] = {g.x, g.y, g.z, g.w};
        #pragma unroll
        for (int j = 0; j < 4; ++j) {
            // inputs are uniform [0,1): b in [0,9]; clamp top for safety.
            int b = (int)(rv[j] * 10.0f);
            b = b > NUM_BINS - 1 ? NUM_BINS - 1 : b;
            int c = (gv[j] > 0.5f) ? b : b + NUM_BINS;  // ano: 0..9, nor: 10..19
            int inc = 1 << ((c & 3) << 3);
            int sel = c >> 2;  // 0..4
            #pragma unroll
            for (int k = 0; k < 5; ++k)
                p[k] += (sel == k) ? inc : 0;   // cmp + cndmask + add, pure VALU
        }
    }

    // Wave butterfly reduce: 2 rounds on packed 8-bit (fields <= 128)...
    #pragma unroll
    for (int k = 0; k < 5; ++k) {
        p[k] += __shfl_xor(p[k], 1, 64);
        p[k] += __shfl_xor(p[k], 2, 64);
    }
    // ...widen to 16-bit fields (10 regs x 2 halves)...
    int q[10];
    #pragma unroll
    for (int k = 0; k < 5; ++k) {
        q[2 * k]     = p[k] & 0x00FF00FF;          // counters 4k+0 (lo16), 4k+2 (hi16)
        q[2 * k + 1] = (p[k] >> 8) & 0x00FF00FF;   // counters 4k+1 (lo16), 4k+3 (hi16)
    }
    // ...4 more rounds on 16-bit packed (fields <= 2048).
    #pragma unroll
    for (int m = 4; m <= 32; m <<= 1) {
        #pragma unroll
        for (int k = 0; k < 10; ++k)
            q[k] += __shfl_xor(q[k], m, 64);
    }

    __shared__ int part[4][2 * NUM_BINS];
    if (lane == 0) {
        #pragma unroll
        for (int k = 0; k < 5; ++k) {
            part[wv][4 * k + 0] = q[2 * k] & 0xFFFF;
            part[wv][4 * k + 2] = (int)((unsigned)q[2 * k] >> 16);
            part[wv][4 * k + 1] = q[2 * k + 1] & 0xFFFF;
            part[wv][4 * k + 3] = (int)((unsigned)q[2 * k + 1] >> 16);
        }
    }
    __syncthreads();
    if (tid < 2 * NUM_BINS) {
        int s = part[0][tid] + part[1][tid] + part[2][tid] + part[3][tid];
        if (USE_WS) {
            dst[(blockIdx.x << 5) + tid] = s;   // plain store, no contention
        } else {
            if (s) atomicAdd(&dst[tid], s);     // fallback path only
        }
    }
}

__global__ __launch_bounds__(BLOCK) void hist_pass2(
    const int* __restrict__ partial,  // [nb][32]
    int* __restrict__ out,            // [20]
    int nb)
{
    const int c = threadIdx.x & 31;   // column (counter; 20..31 unused)
    const int g = threadIdx.x >> 5;   // 0..7 row-group
    int s = 0;
    for (int r = g; r < nb; r += 8)
        s += partial[(r << 5) + c];   // coalesced 128B rows
    __shared__ int tmp[8][32];
    tmp[g][c] = s;
    __syncthreads();
    if (threadIdx.x < 2 * NUM_BINS) {
        int t = 0;
        #pragma unroll
        for (int i = 0; i < 8; ++i) t += tmp[i][threadIdx.x];
        out[threadIdx.x] = t;
    }
}

extern "C" void kernel_launch(void* const* d_in, const int* in_sizes, int n_in,
                              void* d_out, int out_size, void* d_ws, size_t ws_size,
                              hipStream_t stream) {
    const float* res = (const float*)d_in[0];
    const float* gt  = (const float*)d_in[1];
    int* out = (int*)d_out;

    const int n  = in_sizes[0];   // 16,777,216 (divisible by 4)
    const int n4 = n >> 2;

    const size_t need = (size_t)GRID1 * 32 * sizeof(int);
    if (ws_size >= need) {
        int* ws = (int*)d_ws;
        hist_pass1<true><<<GRID1, BLOCK, 0, stream>>>(res, gt, ws, n4);
        hist_pass2<<<1, BLOCK, 0, stream>>>(ws, out, GRID1);
    } else {
        // Fallback: accumulate straight into d_out with per-block atomics.
        hipMemsetAsync(d_out, 0, 2 * NUM_BINS * sizeof(int), stream);
        hist_pass1<false><<<GRID1, BLOCK, 0, stream>>>(res, gt, out, n4);
    }
}

// Round 3
// 46.932 us; speedup vs baseline: 1.3508x; 1.3508x over previous
//
#include <hip/hip_runtime.h>

#define NUM_BINS 10
#define GRID1 2048
#define BLOCK 256
// 16,777,216 elems / (2048*256 threads) = 32 elems/thread = 8 float4 quads,
// processed as 2 batches x 4 quads/stream (8 loads in flight per batch).
// Packed 8-bit counter fields: max 32/thread -> 128 after 2 butterfly rounds;
// 16-bit fields after full wave reduce hold <= 2048. No overflow.

__device__ __forceinline__ void accum_quad(const float4& r, const float4& g, int p[5]) {
    float rv[4] = {r.x, r.y, r.z, r.w};
    float gv[4] = {g.x, g.y, g.z, g.w};
    #pragma unroll
    for (int j = 0; j < 4; ++j) {
        int b = (int)(rv[j] * 10.0f);          // inputs in [0,1)
        b = b > NUM_BINS - 1 ? NUM_BINS - 1 : b;
        int c = (gv[j] > 0.5f) ? b : b + NUM_BINS;   // ano: 0..9, nor: 10..19
        int inc = 1 << ((c & 3) << 3);
        int sel = c >> 2;                       // 0..4
        #pragma unroll
        for (int k = 0; k < 5; ++k)
            p[k] += (sel == k) ? inc : 0;       // cmp + cndmask + add
    }
}

__global__ __launch_bounds__(BLOCK) void hist_one(
    const float* __restrict__ res,
    const float* __restrict__ gt,
    int* __restrict__ out,   // [20], pre-zeroed
    int n4)
{
    const int tid  = threadIdx.x;
    const int lane = tid & 63;
    const int wv   = tid >> 6;

    int p[5] = {0, 0, 0, 0, 0};

    const float4* __restrict__ res4 = (const float4*)res;
    const float4* __restrict__ gt4  = (const float4*)gt;

    const int S    = GRID1 * BLOCK;            // quad stride
    const int base = blockIdx.x * BLOCK + tid;

    if (n4 == S * 8) {
        // Fast path: exactly 8 quads/thread, 2 batches of 4, loads batched for MLP.
        #pragma unroll
        for (int h = 0; h < 2; ++h) {
            const int i0 = base + h * 4 * S;
            float4 rq0 = res4[i0 + 0 * S];
            float4 rq1 = res4[i0 + 1 * S];
            float4 rq2 = res4[i0 + 2 * S];
            float4 rq3 = res4[i0 + 3 * S];
            float4 gq0 = gt4[i0 + 0 * S];
            float4 gq1 = gt4[i0 + 1 * S];
            float4 gq2 = gt4[i0 + 2 * S];
            float4 gq3 = gt4[i0 + 3 * S];
            accum_quad(rq0, gq0, p);
            accum_quad(rq1, gq1, p);
            accum_quad(rq2, gq2, p);
            accum_quad(rq3, gq3, p);
        }
    } else {
        // Generic grid-stride fallback (counts per field capped by caller sizing).
        for (int i = base; i < n4; i += S)
            accum_quad(res4[i], gt4[i], p);
    }

    // Wave butterfly reduce: 2 rounds on packed 8-bit (fields <= 128)...
    #pragma unroll
    for (int k = 0; k < 5; ++k) {
        p[k] += __shfl_xor(p[k], 1, 64);
        p[k] += __shfl_xor(p[k], 2, 64);
    }
    // ...widen to 16-bit fields (10 regs x 2 halves)...
    int q[10];
    #pragma unroll
    for (int k = 0; k < 5; ++k) {
        q[2 * k]     = p[k] & 0x00FF00FF;          // counters 4k+0 (lo16), 4k+2 (hi16)
        q[2 * k + 1] = (p[k] >> 8) & 0x00FF00FF;   // counters 4k+1 (lo16), 4k+3 (hi16)
    }
    // ...4 more rounds on 16-bit packed (fields <= 2048).
    #pragma unroll
    for (int m = 4; m <= 32; m <<= 1) {
        #pragma unroll
        for (int k = 0; k < 10; ++k)
            q[k] += __shfl_xor(q[k], m, 64);
    }

    __shared__ int part[4][2 * NUM_BINS];
    if (lane == 0) {
        #pragma unroll
        for (int k = 0; k < 5; ++k) {
            part[wv][4 * k + 0] = q[2 * k] & 0xFFFF;
            part[wv][4 * k + 2] = (int)((unsigned)q[2 * k] >> 16);
            part[wv][4 * k + 1] = q[2 * k + 1] & 0xFFFF;
            part[wv][4 * k + 3] = (int)((unsigned)q[2 * k + 1] >> 16);
        }
    }
    __syncthreads();
    // One wave-instruction of global atomics per block (20 lanes, 2 cache lines).
    if (tid < 2 * NUM_BINS) {
        int s = part[0][tid] + part[1][tid] + part[2][tid] + part[3][tid];
        if (s) atomicAdd(&out[tid], s);
    }
}

extern "C" void kernel_launch(void* const* d_in, const int* in_sizes, int n_in,
                              void* d_out, int out_size, void* d_ws, size_t ws_size,
                              hipStream_t stream) {
    const float* res = (const float*)d_in[0];
    const float* gt  = (const float*)d_in[1];
    int* out = (int*)d_out;

    const int n  = in_sizes[0];   // 16,777,216 (divisible by 4)
    const int n4 = n >> 2;

    // Harness poisons d_out with 0xAA; zero it on-stream (capture-safe).
    hipMemsetAsync(d_out, 0, 2 * NUM_BINS * sizeof(int), stream);
    hist_one<<<GRID1, BLOCK, 0, stream>>>(res, gt, out, n4);
}

// Round 4
// 44.005 us; speedup vs baseline: 1.4406x; 1.0665x over previous
//
#include <hip/hip_runtime.h>

#define NUM_BINS 10
#define GRID1 2048
#define BLOCK 256
#define SB() __builtin_amdgcn_sched_barrier(0)
// 16,777,216 elems / (2048*256 threads) = 32 elems/thread = 8 float4 quad-pairs.
// All 16 dwordx4 loads issued before any consumption (sched_barrier-pinned):
// 16 KB in flight per wave. Packed 8-bit counter fields: max 32/thread ->
// 128 after 2 butterfly rounds; 16-bit fields after full reduce <= 2048.

__device__ __forceinline__ void accum_quad(float4 r, float4 g, int p[5]) {
    float rv[4] = {r.x, r.y, r.z, r.w};
    float gv[4] = {g.x, g.y, g.z, g.w};
    #pragma unroll
    for (int j = 0; j < 4; ++j) {
        int b = (int)(rv[j] * 10.0f);          // inputs in [0,1)
        b = b > NUM_BINS - 1 ? NUM_BINS - 1 : b;
        int c = (gv[j] > 0.5f) ? b : b + NUM_BINS;   // ano: 0..9, nor: 10..19
        int inc = 1 << ((c & 3) << 3);
        int sel = c >> 2;                       // 0..4
        #pragma unroll
        for (int k = 0; k < 5; ++k)
            p[k] += (sel == k) ? inc : 0;       // cmp + cndmask + add
    }
}

__global__ __launch_bounds__(BLOCK) void hist_mlp(
    const float* __restrict__ res,
    const float* __restrict__ gt,
    int* __restrict__ out,   // [20], pre-zeroed
    int n4)
{
    const int tid  = threadIdx.x;
    const int lane = tid & 63;
    const int wv   = tid >> 6;

    int p[5] = {0, 0, 0, 0, 0};

    const float4* __restrict__ res4 = (const float4*)res;
    const float4* __restrict__ gt4  = (const float4*)gt;

    const int S    = GRID1 * BLOCK;            // quad stride
    const int base = blockIdx.x * BLOCK + tid;

    if (n4 == S * 8) {
        // Issue ALL 16 loads (interleaved r/g so consumption order matches
        // return order), then fence, then consume. Fully unrolled ->
        // compile-time indices -> registers, no scratch.
        float4 r[8], g[8];
        #pragma unroll
        for (int k = 0; k < 8; ++k) {
            r[k] = res4[base + k * S];
            g[k] = gt4[base + k * S];
        }
        SB();   // do not let the compiler sink loads into the consume chain
        #pragma unroll
        for (int k = 0; k < 8; ++k)
            accum_quad(r[k], g[k], p);
    } else {
        // Generic grid-stride fallback.
        for (int i = base; i < n4; i += S)
            accum_quad(res4[i], gt4[i], p);
    }

    // Wave butterfly reduce: 2 rounds on packed 8-bit (fields <= 128)...
    #pragma unroll
    for (int k = 0; k < 5; ++k) {
        p[k] += __shfl_xor(p[k], 1, 64);
        p[k] += __shfl_xor(p[k], 2, 64);
    }
    // ...widen to 16-bit fields (10 regs x 2 halves)...
    int q[10];
    #pragma unroll
    for (int k = 0; k < 5; ++k) {
        q[2 * k]     = p[k] & 0x00FF00FF;          // counters 4k+0 (lo16), 4k+2 (hi16)
        q[2 * k + 1] = (p[k] >> 8) & 0x00FF00FF;   // counters 4k+1 (lo16), 4k+3 (hi16)
    }
    // ...4 more rounds on 16-bit packed (fields <= 2048).
    #pragma unroll
    for (int m = 4; m <= 32; m <<= 1) {
        #pragma unroll
        for (int k = 0; k < 10; ++k)
            q[k] += __shfl_xor(q[k], m, 64);
    }

    __shared__ int part[4][2 * NUM_BINS];
    if (lane == 0) {
        #pragma unroll
        for (int k = 0; k < 5; ++k) {
            part[wv][4 * k + 0] = q[2 * k] & 0xFFFF;
            part[wv][4 * k + 2] = (int)((unsigned)q[2 * k] >> 16);
            part[wv][4 * k + 1] = q[2 * k + 1] & 0xFFFF;
            part[wv][4 * k + 3] = (int)((unsigned)q[2 * k + 1] >> 16);
        }
    }
    __syncthreads();
    // One wave-instruction of global atomics per block (20 lanes, 2 cache lines).
    if (tid < 2 * NUM_BINS) {
        int s = part[0][tid] + part[1][tid] + part[2][tid] + part[3][tid];
        if (s) atomicAdd(&out[tid], s);
    }
}

extern "C" void kernel_launch(void* const* d_in, const int* in_sizes, int n_in,
                              void* d_out, int out_size, void* d_ws, size_t ws_size,
                              hipStream_t stream) {
    const float* res = (const float*)d_in[0];
    const float* gt  = (const float*)d_in[1];
    int* out = (int*)d_out;

    const int n  = in_sizes[0];   // 16,777,216 (divisible by 4)
    const int n4 = n >> 2;

    // Harness poisons d_out with 0xAA; zero it on-stream (capture-safe).
    hipMemsetAsync(d_out, 0, 2 * NUM_BINS * sizeof(int), stream);
    hist_mlp<<<GRID1, BLOCK, 0, stream>>>(res, gt, out, n4);
}